// Round 21
// baseline (68.354 us; speedup 1.0000x reference)
//
#include <hip/hip_runtime.h>
#include <hip/hip_bf16.h>

// RingConv2d via f16 MFMA implicit GEMM (v21 = 4-waves/SIMD occupancy point).
// GEMM: M=o(128), N=px(32*64*64), K=1152 = 4cg x 9 taps x 2 kk x (8c x 2trig)
// MFMA 32x32x16_f16, consistent A/B k-permutation. C/D (measured):
//   col=lane&31, row=(reg&3)+8*(reg>>2)+4*(lane>>5).
// v21: wave = 2 o-frag x 2 rows (acc 64 AGPR) -> total regs target <=128
//   (m69 cliff) -> 4 waves/SIMD, the ONLY untested occupancy regime (all
//   r8-r20 ran <=2/SIMD). Feed ratio per step (4 MFMA : 2 B ds_read + 2 A)
//   equals r9's best; latency covered by 4x TLP instead of ILP.
// Block 256 thr = 4 waves (2 o-groups x 2 row-groups); tile 128o x 4r x 32c;
//   grid 1024 XCD-swizzled; LDS dbuf 2x16KB (quad-major gload_lds, proven
//   conflict-free); A-ring depth 2; counted vmcnt(4); setprio kept (r17: +30%).

typedef _Float16 half8 __attribute__((ext_vector_type(8)));
typedef float f32x16 __attribute__((ext_vector_type(16)));

#define NB 32
#define NC 64
#define NH 64
#define NW 64
#define NO 128
#define PW 66
#define TROWS 6
#define TCOLS 34
#define TPX (TROWS * TCOLS)    // 204 pixels
#define NVALID (TPX * 4)       // 816 valid uint4 slots
#define NSLOT 1024             // padded to 4*256 (scratch tail)

union U16 { unsigned short u; _Float16 h; };
union HB { uint4 u4; half8 h; };

__device__ inline unsigned pack_cs(float ang) {
    float s, c;
    sincosf(ang, &s, &c);
    U16 uc, us; uc.h = (_Float16)c; us.h = (_Float16)s;
    return (unsigned)uc.u | ((unsigned)us.u << 16);   // cos low, sin high
}

__device__ inline unsigned pack_cs_fast(float ang) {
    float s, c;
    __sincosf(ang, &s, &c);
    U16 uc, us; uc.h = (_Float16)c; us.h = (_Float16)s;
    return (unsigned)uc.u | ((unsigned)us.u << 16);
}

// ---- single prep dispatch: x-pack (2048 blocks) + w-pack (72) + border (128)
__global__ __launch_bounds__(256) void prep_all(const float* __restrict__ x,
                                                const float* __restrict__ w,
                                                uint4* __restrict__ xp,
                                                uint4* __restrict__ wqa) {
    __shared__ unsigned ls[64 * 65];
    const int blk = blockIdx.x;
    const int t = threadIdx.x;

    if (blk < NB * NH) {
        const int b = blk >> 6, row = blk & 63;
#pragma unroll
        for (int pass = 0; pass < 16; ++pass) {
            int c = pass * 4 + (t >> 6);
            int col = t & 63;
            float v = x[((size_t)(b * NC + c) * NH + row) * NW + col];
            ls[c * 65 + col] = pack_cs_fast(v);
        }
        __syncthreads();
        const int q = t & 3, col = t >> 2;
#pragma unroll
        for (int cg = 0; cg < 4; ++cg) {
            uint4 vv;
            vv.x = ls[(cg * 16 + 4 * q + 0) * 65 + col];
            vv.y = ls[(cg * 16 + 4 * q + 1) * 65 + col];
            vv.z = ls[(cg * 16 + 4 * q + 2) * 65 + col];
            vv.w = ls[(cg * 16 + 4 * q + 3) * 65 + col];
            xp[(size_t)(((b * 4 + cg) * PW + row + 1) * PW + col + 1) * 4 + q] = vv;
        }
    } else if (blk < NB * NH + 72) {
        // w: OIHW f32 -> wqa[(cg*9+kpos)*2+kk][o128][g2], 16B lane frag =
        // channels {8kk+4g2 .. +3} x (cos,sin)
        int tt = (blk - NB * NH) * 256 + t;          // 36*2*128*2 = 18432
        if (tt < 36 * 2 * 128 * 2) {
            int g2 = tt & 1, o = (tt >> 1) & 127, kk = (tt >> 8) & 1, chunk = tt >> 9;
            int cg = chunk / 9, kpos = chunk % 9, kh = kpos / 3, kw = kpos % 3;
            unsigned r[4];
#pragma unroll
            for (int m = 0; m < 4; ++m) {
                int c = cg * 16 + kk * 8 + g2 * 4 + m;
                float ang = w[((o * NC + c) * 3 + kh) * 3 + kw];
                r[m] = pack_cs(ang);
            }
            wqa[tt] = make_uint4(r[0], r[1], r[2], r[3]);
        }
    } else {
        const int bc = blk - NB * NH - 72;           // 0..127 = b*4+cg
        uint4* base = xp + (size_t)bc * PW * PW * 4;
        const uint4 v = make_uint4(0x3C00u, 0x3C00u, 0x3C00u, 0x3C00u);
        for (int idx = t; idx < 260 * 4; idx += 256) {
            int p = idx >> 2, q = idx & 3;
            int r, c;
            if (p < 66)       { r = 0;       c = p; }
            else if (p < 132) { r = 65;      c = p - 66; }
            else if (p < 196) { r = p - 131; c = 0; }
            else              { r = p - 195; c = 65; }
            base[(size_t)(r * PW + c) * 4 + q] = v;
        }
    }
}

#define GLOAD16(gptr, ldsptr)                                                   \
    __builtin_amdgcn_global_load_lds(                                           \
        (const __attribute__((address_space(1))) unsigned*)(gptr),              \
        (__attribute__((address_space(3))) unsigned*)(ldsptr), 16, 0, 0)

// ---- conv v21: block = 256 thr / 4 waves; 128 o x 4 rows x 32 cols;
//      wave = 2 o-frag x 2 rows (acc 64 AGPR -> 4 waves/SIMD target)
__global__ __launch_bounds__(256, 4) void ring_conv(const uint4* __restrict__ xp,
                                                    const uint4* __restrict__ wqa,
                                                    float* __restrict__ out) {
    __shared__ __align__(16) char xs[2][NSLOT * 16];   // 2 x 16384 B

    // chunked XCD swizzle (bijective: 1024 = 8*128)
    const int d = blockIdx.x;
    const int blk = (d & 7) * 128 + (d >> 3);

    const int ch2 = blk & 1, rq = (blk >> 1) & 15, b = blk >> 5;
    const int row0 = rq * 4, col0 = ch2 * 32;

    const int t = threadIdx.x, lane = t & 63, wid = t >> 6;   // wid 0..3
    const int l31 = lane & 31, g2 = lane >> 5;
    const int op = wid & 1, rg = wid >> 1;             // o-pair, row-group 0..1
    const int rowbase = rg * 2;                        // wave's 2 rows

    f32x16 acc[2][2] = {};                             // [o-frag f][px-row r]

    // staging: slot e = k*256 + t (quad-major: q = e/204, p = e%204);
    // 4 passes; slots >= 816 -> clamped source, scratch dest.
    int goff[4];
#pragma unroll
    for (int k = 0; k < 4; ++k) {
        int e = k * 256 + t;
        if (e > NVALID - 1) e = NVALID - 1;
        int q = e / TPX, p = e - q * TPX;
        int rr = p / TCOLS, cc = p - rr * TCOLS;
        goff[k] = ((row0 + rr) * PW + (col0 + cc)) * 4 + q;
    }
    const size_t img_stride = (size_t)PW * PW * 4;
    const uint4* img0 = xp + (size_t)(b * 4) * img_stride;

#define STAGE(bufi, cgi)                                                        \
    {   const uint4* img = img0 + (size_t)(cgi) * img_stride;                   \
        _Pragma("unroll")                                                       \
        for (int k = 0; k < 4; ++k)                                             \
            GLOAD16(img + goff[k], &xs[bufi][(size_t)(k * 256 + wid * 64) * 16]); }

    const uint4* wbase = wqa + (op * 64 + l31) * 2 + g2;

    // prologue: stage cg0 -> buf0
    STAGE(0, 0)
    asm volatile("s_waitcnt vmcnt(0)" ::: "memory");
    __builtin_amdgcn_sched_barrier(0);
    __builtin_amdgcn_s_barrier();

#pragma unroll
    for (int cg = 0; cg < 4; ++cg) {
        const int cur = cg & 1;
        const uint4* wa = wbase + (size_t)(cg * 18) * 256;

        // (1) A ring depth 2 (4 loads) -- BEFORE stage (vmcnt FIFO)
        HB Ar[2][2];                                   // [s&1][f]
#pragma unroll
        for (int i = 0; i < 2; ++i)
#pragma unroll
            for (int f = 0; f < 2; ++f)
                Ar[i][f].u4 = wa[i * 256 + f * 64];

        // (2) next-cg stage; vmcnt(4) drains A-preloads + old stage,
        //     keeps the 4 new stage loads in flight
        if (cg < 3) {
            STAGE(cur ^ 1, cg + 1)
            asm volatile("s_waitcnt vmcnt(4)" ::: "memory");
        } else {
            asm volatile("s_waitcnt vmcnt(0)" ::: "memory");
        }
        __builtin_amdgcn_sched_barrier(0);
        __builtin_amdgcn_s_barrier();                  // buf cur complete

        const char* xbuf = xs[cur];

        // (3) B(0) preload: slot (2*kk+g2)*204 + row*34 + col
        HB Bop[2][2];
#pragma unroll
        for (int r = 0; r < 2; ++r)
            Bop[0][r].u4 = *(const uint4*)(xbuf
                + (size_t)(g2 * TPX + (rowbase + r) * TCOLS + l31) * 16);

        // (4) 18 K-steps: 4 MFMA each; B dbuf; A ring refill (depth 2)
#pragma unroll
        for (int s = 0; s < 18; ++s) {                 // s = kpos*2 + kk
            const int cp = s & 1, np = cp ^ 1;
            if (s < 17) {                              // prefetch B(s+1)
                const int s1 = s + 1, kp1 = s1 >> 1, kk1 = s1 & 1;
                const int kh1 = kp1 / 3, kw1 = kp1 % 3;
#pragma unroll
                for (int r = 0; r < 2; ++r)
                    Bop[np][r].u4 = *(const uint4*)(xbuf
                        + (size_t)((2 * kk1 + g2) * TPX
                                   + (rowbase + r + kh1) * TCOLS + l31 + kw1) * 16);
            }
            __builtin_amdgcn_s_setprio(1);
#pragma unroll
            for (int r = 0; r < 2; ++r)
#pragma unroll
                for (int f = 0; f < 2; ++f)
                    acc[f][r] = __builtin_amdgcn_mfma_f32_32x32x16_f16(
                        Ar[cp][f].h, Bop[cp][r].h, acc[f][r], 0, 0, 0);
            __builtin_amdgcn_s_setprio(0);
            if (s < 16) {                              // refill ring with A(s+2)
#pragma unroll
                for (int f = 0; f < 2; ++f)
                    Ar[cp][f].u4 = wa[(s + 2) * 256 + f * 64];
            }
        }

        __builtin_amdgcn_s_barrier();                  // reads of buf cur done
    }

    // epilogue: D col=l31, o = op*64 + 32f + (reg&3)+8*(reg>>2)+4*g2
#pragma unroll
    for (int f = 0; f < 2; ++f)
#pragma unroll
        for (int r = 0; r < 2; ++r) {
            const int orow = row0 + rowbase + r;
#pragma unroll
            for (int reg = 0; reg < 16; ++reg) {
                int o = op * 64 + f * 32 + (reg & 3) + 8 * (reg >> 2) + 4 * g2;
                out[(((size_t)b * NO + o) * NH + orow) * NW + col0 + l31] = acc[f][r][reg];
            }
        }
}

extern "C" void kernel_launch(void* const* d_in, const int* in_sizes, int n_in,
                              void* d_out, int out_size, void* d_ws, size_t ws_size,
                              hipStream_t stream) {
    const float* x = (const float*)d_in[0];
    const float* w = (const float*)d_in[1];

    uint4* xpnt = (uint4*)d_ws;                                  // 35.7 MB padded
    uint4* wqp = (uint4*)((char*)d_ws + (size_t)36 * 1024 * 1024);

    prep_all<<<NB * NH + 72 + 128, 256, 0, stream>>>(x, w, xpnt, wqp);
    ring_conv<<<1024, 256, 0, stream>>>(xpnt, wqp, (float*)d_out);
}

// Round 22
// 57.216 us; speedup vs baseline: 1.1947x; 1.1947x over previous
//
#include <hip/hip_runtime.h>
#include <hip/hip_bf16.h>

// RingConv2d via f16 MFMA implicit GEMM (v22 = exact r9/r18 restore — measured optimum).
// GEMM: M=o(128), N=px(32*64*64), K=1152 = 4cg x 9 taps x 2 kk x (8c x 2trig)
// MFMA 32x32x16_f16, consistent A/B k-permutation (k-order cancels in dot).
// C/D (measured): col=lane&31, row=(reg&3)+8*(reg>>2)+4*(lane>>5).
// Wave = 2 o-frags x 4 px-rows = 8 MFMA/step vs 4 LDS B-frags (B reuse x2).
// vmcnt FIFO: A ring (depth 4) + B(0) preloaded BEFORE the S stage loads.
// s_setprio(1) around MFMA is ESSENTIAL (r17 ablation: removing = 44->57us).
// Campaign (r8-r21): occupancy x ILP matrix fully measured — 1/2/4 waves-per-
// SIMD x 4/8/16-MFMA ILP all in 42-57us band; this config is the interior
// optimum (conv 42-44us, MfmaUtil ~35%, no pipe saturated).

typedef _Float16 half8 __attribute__((ext_vector_type(8)));
typedef float f32x16 __attribute__((ext_vector_type(16)));

#define NB 32
#define NC 64
#define NH 64
#define NW 64
#define NO 128
#define PW 66
#define PSTRIDE 72    // LDS bytes per pixel
#define TROWS 10
#define TCOLS 34
#define TPX (TROWS * TCOLS)   // 340 staged pixels

union U16 { unsigned short u; _Float16 h; };
union HB { uint4 u4; unsigned long long q[2]; half8 h; };

__device__ inline unsigned pack_cs(float ang) {
    float s, c;
    sincosf(ang, &s, &c);
    U16 uc, us; uc.h = (_Float16)c; us.h = (_Float16)s;
    return (unsigned)uc.u | ((unsigned)us.u << 16);   // cos low, sin high
}

__device__ inline unsigned pack_cs_fast(float ang) {
    float s, c;
    __sincosf(ang, &s, &c);
    U16 uc, us; uc.h = (_Float16)c; us.h = (_Float16)s;
    return (unsigned)uc.u | ((unsigned)us.u << 16);
}

// ---- single prep dispatch: x-pack (2048 blocks) + w-pack (72) + border (128)
__global__ __launch_bounds__(256) void prep_all(const float* __restrict__ x,
                                                const float* __restrict__ w,
                                                uint4* __restrict__ xp,
                                                uint4* __restrict__ wqa) {
    __shared__ unsigned ls[64 * 65];
    const int blk = blockIdx.x;
    const int t = threadIdx.x;

    if (blk < NB * NH) {
        // x: [b][c][h][w] f32 -> xp[b][cg][1+row][1+col] 64B pixel,
        // quad q = channels {4q..4q+3} x (cos,sin)
        const int b = blk >> 6, row = blk & 63;
#pragma unroll
        for (int pass = 0; pass < 16; ++pass) {
            int c = pass * 4 + (t >> 6);
            int col = t & 63;
            float v = x[((size_t)(b * NC + c) * NH + row) * NW + col];
            ls[c * 65 + col] = pack_cs_fast(v);
        }
        __syncthreads();
        const int q = t & 3, col = t >> 2;
#pragma unroll
        for (int cg = 0; cg < 4; ++cg) {
            uint4 vv;
            vv.x = ls[(cg * 16 + 4 * q + 0) * 65 + col];
            vv.y = ls[(cg * 16 + 4 * q + 1) * 65 + col];
            vv.z = ls[(cg * 16 + 4 * q + 2) * 65 + col];
            vv.w = ls[(cg * 16 + 4 * q + 3) * 65 + col];
            xp[(size_t)(((b * 4 + cg) * PW + row + 1) * PW + col + 1) * 4 + q] = vv;
        }
    } else if (blk < NB * NH + 72) {
        // w: OIHW f32 -> wqa[(cg*9+kpos)*2+kk][o128][g2] 16B A-fragments,
        // lane 16B = channels {8kk+4g2 .. +3} x (cos,sin)
        int tt = (blk - NB * NH) * 256 + t;          // 36*2*128*2 = 18432
        if (tt < 36 * 2 * 128 * 2) {
            int g2 = tt & 1, o = (tt >> 1) & 127, kk = (tt >> 8) & 1, chunk = tt >> 9;
            int cg = chunk / 9, kpos = chunk % 9, kh = kpos / 3, kw = kpos % 3;
            unsigned r[4];
#pragma unroll
            for (int m = 0; m < 4; ++m) {
                int c = cg * 16 + kk * 8 + g2 * 4 + m;
                float ang = w[((o * NC + c) * 3 + kh) * 3 + kw];
                r[m] = pack_cs(ang);
            }
            wqa[tt] = make_uint4(r[0], r[1], r[2], r[3]);
        }
    } else {
        // border pixels = (cos,sin)=(1,0)
        const int bc = blk - NB * NH - 72;           // 0..127 = b*4+cg
        uint4* base = xp + (size_t)bc * PW * PW * 4;
        const uint4 v = make_uint4(0x3C00u, 0x3C00u, 0x3C00u, 0x3C00u);
        for (int idx = t; idx < 260 * 4; idx += 256) {
            int p = idx >> 2, q = idx & 3;
            int r, c;
            if (p < 66)       { r = 0;       c = p; }
            else if (p < 132) { r = 65;      c = p - 66; }
            else if (p < 196) { r = p - 131; c = 0; }
            else              { r = p - 195; c = 65; }
            base[(size_t)(r * PW + c) * 4 + q] = v;
        }
    }
}

// ---- conv: block = 128 o x (8x32) px, 4 waves x (2 o-frag x 4 rows)
__global__ __launch_bounds__(256, 2) void ring_conv(const uint4* __restrict__ xp,
                                                    const uint4* __restrict__ wqa,
                                                    float* __restrict__ out) {
    __shared__ __align__(16) char xs[TPX * PSTRIDE];   // 24480 B

    // chunked XCD swizzle (bijective: 512 = 8*64)
    const int d = blockIdx.x;
    const int blk = (d & 7) * 64 + (d >> 3);

    const int ch = blk & 1, rq = (blk >> 1) & 7, b = blk >> 4;
    const int row0 = rq * 8, col0 = ch * 32;

    const int t = threadIdx.x, lane = t & 63, wid = t >> 6;
    const int l31 = lane & 31, g2 = lane >> 5;
    const int op = wid & 1, rg = wid >> 1;             // o-pair, row-group
    const int rowbase = rg * 4;

    f32x16 acc[2][4] = {};                             // [o-frag f][px-row r]

    // staging geometry: 340 px x 4 quads = 1360 uint4; 6 passes, last partial
    int goff[6], loff[6];
#pragma unroll
    for (int k = 0; k < 6; ++k) {
        int e = k * 256 + t;
        if (e > TPX * 4 - 1) e = TPX * 4 - 1;          // dup tail benign
        int p = e >> 2, q = e & 3;
        int rr = p / TCOLS, cc = p - rr * TCOLS;
        goff[k] = ((row0 + rr) * PW + (col0 + cc)) * 4 + q;
        loff[k] = p * PSTRIDE + q * 16;
    }
    const size_t img_stride = (size_t)PW * PW * 4;
    const uint4* img0 = xp + (size_t)(b * 4) * img_stride;

    const int xlane = l31 * PSTRIDE + g2 * 16;
    // A: frag f covers o = op*64 + 32f + l31, half g2
    const uint4* wbase = wqa + (op * 64 + l31) * 2 + g2;

    // prologue: stage cg0
    {
        uint4 S[6];
#pragma unroll
        for (int k = 0; k < 6; ++k) S[k] = img0[goff[k]];
#pragma unroll
        for (int k = 0; k < 6; ++k) {
            char* dst = xs + loff[k];
            *(unsigned long long*)dst = (unsigned long long)S[k].x | ((unsigned long long)S[k].y << 32);
            *(unsigned long long*)(dst + 8) = (unsigned long long)S[k].z | ((unsigned long long)S[k].w << 32);
        }
    }
    __syncthreads();

    for (int cg = 0; cg < 4; ++cg) {
        const uint4* wa = wbase + (size_t)(cg * 18) * 256;

        // (1) A ring depth 4 + B(0) preloads -- BEFORE S loads (vmcnt FIFO)
        HB Ar[4][2];
#pragma unroll
        for (int i = 0; i < 4; ++i) {
            Ar[i][0].u4 = wa[i * 256];
            Ar[i][1].u4 = wa[i * 256 + 64];
        }
        HB Bop[2][4];
#pragma unroll
        for (int r = 0; r < 4; ++r) {
            const char* sp = xs + (rowbase + r) * TCOLS * PSTRIDE + xlane;
            Bop[0][r].q[0] = *(const unsigned long long*)sp;
            Bop[0][r].q[1] = *(const unsigned long long*)(sp + 8);
        }

        // (2) next-cg stage loads, in flight under the whole cg compute
        uint4 S[6];
        if (cg < 3) {
            const uint4* img = img0 + (size_t)(cg + 1) * img_stride;
#pragma unroll
            for (int k = 0; k < 6; ++k) S[k] = img[goff[k]];
        }

        // (3) 18 K-steps, fully unrolled (ring indices static)
#pragma unroll
        for (int s = 0; s < 18; ++s) {
            const int cp = s & 1, np = cp ^ 1;
            if (s < 17) {                              // prefetch B(s+1)
                const int s1 = s + 1, kp1 = s1 >> 1, kk1 = s1 & 1;
                const int kh1 = kp1 / 3, kw1 = kp1 % 3;
#pragma unroll
                for (int r = 0; r < 4; ++r) {
                    const char* sp = xs
                        + (((rowbase + r + kh1) * TCOLS + kw1) * PSTRIDE + kk1 * 32) + xlane;
                    Bop[np][r].q[0] = *(const unsigned long long*)sp;
                    Bop[np][r].q[1] = *(const unsigned long long*)(sp + 8);
                }
            }
            __builtin_amdgcn_s_setprio(1);
#pragma unroll
            for (int r = 0; r < 4; ++r)
#pragma unroll
                for (int f = 0; f < 2; ++f)
                    acc[f][r] = __builtin_amdgcn_mfma_f32_32x32x16_f16(
                        Ar[s & 3][f].h, Bop[cp][r].h, acc[f][r], 0, 0, 0);
            __builtin_amdgcn_s_setprio(0);
            if (s < 14) {                              // refill ring slot with A(s+4)
                Ar[s & 3][0].u4 = wa[(s + 4) * 256];
                Ar[s & 3][1].u4 = wa[(s + 4) * 256 + 64];
            }
        }

        __syncthreads();                               // xs reads done
        if (cg < 3) {
#pragma unroll
            for (int k = 0; k < 6; ++k) {
                char* dst = xs + loff[k];
                *(unsigned long long*)dst = (unsigned long long)S[k].x | ((unsigned long long)S[k].y << 32);
                *(unsigned long long*)(dst + 8) = (unsigned long long)S[k].z | ((unsigned long long)S[k].w << 32);
            }
            __syncthreads();                           // xs(cg+1) visible
        }
    }

    // epilogue: D col=l31, o = op*64 + 32f + (reg&3)+8*(reg>>2)+4*g2
#pragma unroll
    for (int f = 0; f < 2; ++f)
#pragma unroll
        for (int r = 0; r < 4; ++r) {
            const int orow = row0 + rowbase + r;
#pragma unroll
            for (int reg = 0; reg < 16; ++reg) {
                int o = op * 64 + f * 32 + (reg & 3) + 8 * (reg >> 2) + 4 * g2;
                out[(((size_t)b * NO + o) * NH + orow) * NW + col0 + l31] = acc[f][r][reg];
            }
        }
}

extern "C" void kernel_launch(void* const* d_in, const int* in_sizes, int n_in,
                              void* d_out, int out_size, void* d_ws, size_t ws_size,
                              hipStream_t stream) {
    const float* x = (const float*)d_in[0];
    const float* w = (const float*)d_in[1];

    uint4* xpnt = (uint4*)d_ws;                                  // 35.7 MB padded
    uint4* wqp = (uint4*)((char*)d_ws + (size_t)36 * 1024 * 1024);

    prep_all<<<NB * NH + 72 + 128, 256, 0, stream>>>(x, w, xpnt, wqp);
    ring_conv<<<512, 256, 0, stream>>>(xpnt, wqp, (float*)d_out);
}